// Round 1
// baseline (48789.224 us; speedup 1.0000x reference)
//
#include <hip/hip_runtime.h>
#include <math.h>

#define T_STEPS 200
#define BATCH   64
#define VOCAB   256
#define EMB     512
#define HN      1024   // NN
#define ON_     1024

// ---------------------------------------------------------------------------
// Generic tiled f32 GEMM:
//   C[M,N] = concat(A1[M,K1], A2[M,K2]) @ W[K1+K2, N] + bias(N)   (opt. ReLU)
// Row-major everywhere. M, N multiples of 64; K1+K2 multiple of 16.
// Block: 256 threads (16x16), 64x64 tile, 4x4 micro-tile per thread.
// ---------------------------------------------------------------------------
__global__ __launch_bounds__(256)
void gemm_f32(const float* __restrict__ A1, int K1,
              const float* __restrict__ A2, int K2,
              const float* __restrict__ W,
              const float* __restrict__ bias,
              float* __restrict__ C,
              int M, int N, int relu)
{
    const int BM = 64, BN = 64, BK = 16;
    __shared__ float As[16][65];   // [k][m], padded: conflict-free write/read
    __shared__ float Bs[16][64];   // [k][n]

    const int tid = threadIdx.x;
    const int tx = tid & 15, ty = tid >> 4;
    const int m0 = blockIdx.y * BM;
    const int n0 = blockIdx.x * BN;
    const int K = K1 + K2;

    float acc[4][4] = {};

    for (int kk = 0; kk < K; kk += BK) {
        // A tile: 64 rows x 16 k-cols, 1024 elems, 4 per thread
        #pragma unroll
        for (int i = 0; i < 4; ++i) {
            int e = tid + i * 256;
            int r = e >> 4, kc = e & 15;
            int gk = kk + kc;
            float v;
            if (gk < K1) v = A1[(size_t)(m0 + r) * K1 + gk];
            else         v = A2[(size_t)(m0 + r) * K2 + (gk - K1)];
            As[kc][r] = v;
        }
        // B tile: 16 k-rows x 64 n-cols, coalesced
        #pragma unroll
        for (int i = 0; i < 4; ++i) {
            int e = tid + i * 256;
            int r = e >> 6, nc = e & 63;
            Bs[r][nc] = W[(size_t)(kk + r) * N + n0 + nc];
        }
        __syncthreads();

        #pragma unroll
        for (int k = 0; k < BK; ++k) {
            float a[4], b[4];
            #pragma unroll
            for (int i = 0; i < 4; ++i) a[i] = As[k][ty * 4 + i];
            #pragma unroll
            for (int j = 0; j < 4; ++j) b[j] = Bs[k][tx * 4 + j];
            #pragma unroll
            for (int i = 0; i < 4; ++i)
                #pragma unroll
                for (int j = 0; j < 4; ++j)
                    acc[i][j] = fmaf(a[i], b[j], acc[i][j]);
        }
        __syncthreads();
    }

    #pragma unroll
    for (int i = 0; i < 4; ++i) {
        int gm = m0 + ty * 4 + i;
        #pragma unroll
        for (int j = 0; j < 4; ++j) {
            int gn = n0 + tx * 4 + j;
            float v = acc[i][j] + (bias ? bias[gn] : 0.0f);
            if (relu) v = fmaxf(v, 0.0f);
            C[(size_t)gm * N + gn] = v;
        }
    }
}

// ---------------------------------------------------------------------------
// LSTM gates: s is (B, 4*HN) with layout [f | i | o | tanh_arg].
// c_new = sig(f)*c + sig(i)*tanh(g); h_new = sig(o)*tanh(c_new)
// ---------------------------------------------------------------------------
__device__ __forceinline__ float sigmoidf_(float x) {
    return 1.0f / (1.0f + __expf(-x));
}

__global__ __launch_bounds__(256)
void lstm_gates(const float* __restrict__ s,
                float* __restrict__ h, float* __restrict__ c,
                float* __restrict__ hs_out)
{
    int idx = blockIdx.x * 256 + threadIdx.x;   // 0 .. B*HN-1
    int b = idx >> 10;                          // / HN
    int j = idx & 1023;                         // % HN
    const float* sr = s + (size_t)b * (4 * HN);
    float fg = sigmoidf_(sr[j]);
    float ig = sigmoidf_(sr[HN + j]);
    float og = sigmoidf_(sr[2 * HN + j]);
    float gg = tanhf(sr[3 * HN + j]);
    float cn = fg * c[idx] + ig * gg;
    float hn = og * tanhf(cn);
    c[idx] = cn;
    h[idx] = hn;
    if (hs_out) hs_out[idx] = hn;
}

// copy initial states from inputs into workspace
__global__ __launch_bounds__(256)
void init_states(const float* __restrict__ a, const float* __restrict__ b,
                 const float* __restrict__ cc, const float* __restrict__ d,
                 float* __restrict__ oa, float* __restrict__ ob,
                 float* __restrict__ oc, float* __restrict__ od, int n)
{
    int i = blockIdx.x * 256 + threadIdx.x;
    if (i < n) { oa[i] = a[i]; ob[i] = b[i]; oc[i] = cc[i]; od[i] = d[i]; }
}

extern "C" void kernel_launch(void* const* d_in, const int* in_sizes, int n_in,
                              void* d_out, int out_size, void* d_ws, size_t ws_size,
                              hipStream_t stream) {
    const float* inputs     = (const float*)d_in[0];   // (T,B,V)
    const float* h0_in      = (const float*)d_in[1];
    const float* c0_in      = (const float*)d_in[2];
    const float* h1_in      = (const float*)d_in[3];
    const float* c1_in      = (const float*)d_in[4];
    const float* emb_matrix = (const float*)d_in[5];   // (V,E)
    const float* lstm_w0    = (const float*)d_in[6];   // (E+HN, 4HN)
    const float* lstm_b0    = (const float*)d_in[7];
    const float* lstm_w1    = (const float*)d_in[8];   // (2HN, 4HN)
    const float* lstm_b1    = (const float*)d_in[9];
    const float* out_w0     = (const float*)d_in[10];  // (HN, ON)
    const float* out_b0     = (const float*)d_in[11];
    const float* out_w1     = (const float*)d_in[12];  // (ON, V)
    const float* out_b1     = (const float*)d_in[13];
    float* logits = (float*)d_out;                     // (T*B, V)

    // workspace layout (floats)
    float* ws   = (float*)d_ws;
    float* emb  = ws;                                      // T*B*E = 6,553,600
    float* sbuf = emb  + (size_t)T_STEPS * BATCH * EMB;    // B*4HN =   262,144
    float* h0   = sbuf + (size_t)BATCH * 4 * HN;           // B*HN
    float* c0   = h0   + (size_t)BATCH * HN;
    float* h1   = c0   + (size_t)BATCH * HN;
    float* c1   = h1   + (size_t)BATCH * HN;
    float* HS   = c1   + (size_t)BATCH * HN;               // T*B*HN = 13,107,200
    float* hid  = HS   + (size_t)T_STEPS * BATCH * HN;     // T*B*ON = 13,107,200
    // total ~133 MB

    const int MB = T_STEPS * BATCH;  // 12800

    init_states<<<dim3((BATCH * HN + 255) / 256), 256, 0, stream>>>(
        h0_in, c0_in, h1_in, c1_in, h0, c0, h1, c1, BATCH * HN);

    // emb = inputs @ emb_matrix           (12800 x 256) @ (256 x 512)
    gemm_f32<<<dim3(EMB / 64, MB / 64), 256, 0, stream>>>(
        inputs, VOCAB, nullptr, 0, emb_matrix, nullptr, emb, MB, EMB, 0);

    for (int t = 0; t < T_STEPS; ++t) {
        // layer 0: s = [e_t, h0] @ W0 + b0    (64 x 1536) @ (1536 x 4096)
        gemm_f32<<<dim3(4 * HN / 64, 1), 256, 0, stream>>>(
            emb + (size_t)t * BATCH * EMB, EMB, h0, HN,
            lstm_w0, lstm_b0, sbuf, BATCH, 4 * HN, 0);
        lstm_gates<<<dim3(BATCH * HN / 256), 256, 0, stream>>>(
            sbuf, h0, c0, nullptr);
        // layer 1: s = [h0_new, h1] @ W1 + b1 (64 x 2048) @ (2048 x 4096)
        gemm_f32<<<dim3(4 * HN / 64, 1), 256, 0, stream>>>(
            h0, HN, h1, HN, lstm_w1, lstm_b1, sbuf, BATCH, 4 * HN, 0);
        lstm_gates<<<dim3(BATCH * HN / 256), 256, 0, stream>>>(
            sbuf, h1, c1, HS + (size_t)t * BATCH * HN);
    }

    // hid = relu(HS @ out_w0 + out_b0)    (12800 x 1024) @ (1024 x 1024)
    gemm_f32<<<dim3(ON_ / 64, MB / 64), 256, 0, stream>>>(
        HS, HN, nullptr, 0, out_w0, out_b0, hid, MB, ON_, 1);

    // logits = hid @ out_w1 + out_b1      (12800 x 1024) @ (1024 x 256)
    gemm_f32<<<dim3(VOCAB / 64, MB / 64), 256, 0, stream>>>(
        hid, ON_, nullptr, 0, out_w1, out_b1, logits, MB, VOCAB, 0);
}

// Round 2
// 17228.206 us; speedup vs baseline: 2.8319x; 2.8319x over previous
//
#include <hip/hip_runtime.h>
#include <math.h>

#define T_STEPS 200
#define BATCH   64
#define VOCAB   256
#define EMB     512
#define HN      1024
#define ON_     1024
#define SDIM    4096   // 4*HN

__device__ __forceinline__ float sigmoidf_(float x) {
    return 1.0f / (1.0f + __expf(-x));
}

// ---------------------------------------------------------------------------
// Fused LSTM cell: s = concat(A1[64,K1], A2[64,K2]) @ W[K1+K2,4096] + bias,
// then gates -> c,h update. Grid: 256 blocks x 512 threads.
// Block b owns h-cols [4b,4b+4): the gate bundle of 16 s-cols
//   local c = g*4+i  <->  global scol = g*1024 + 4b + i   (g=0..3: f,i,o,g)
// Within block: 8 waves K-split; lane p: rows r0=(p&15)*4, cols c0=(p>>4)*4.
// Deterministic cross-wave reduce via LDS tree (fixed order, no atomics).
// ---------------------------------------------------------------------------
__global__ __launch_bounds__(512)
void lstm_cell(const float* __restrict__ A1, int K1,
               const float* __restrict__ A2, int K2,
               const float* __restrict__ W,
               const float* __restrict__ bias,
               float* __restrict__ cst,
               float* __restrict__ h_out,
               float* __restrict__ hs_out)
{
    __shared__ float As[64][66];        // [k][row], stride 66 -> 8B-aligned float2, 2-way max
    __shared__ float Ws[64][16];        // [k][local c], b128 reads conflict-free
    __shared__ float Pred[8][64][17];   // wave partials, +1 pad kills 32-way on write
    __shared__ float Sx[16][66];        // reduced s, gate-bundled

    const int tid  = threadIdx.x;
    const int wv   = tid >> 6;          // 0..7
    const int lane = tid & 63;
    const int r0   = (lane & 15) << 2;
    const int c0   = (lane >> 4) << 2;
    const int colbase = blockIdx.x << 2;
    const int K   = K1 + K2;
    const int NKB = K >> 6;             // BK = 64

    float acc[4][4] = {};
    float4 pa[2];
    float  pw[2];

    // prologue prefetch (kb = 0)
    {
        #pragma unroll
        for (int q = 0; q < 2; ++q) {
            int e = tid + (q << 9);
            int r = e >> 4, k4 = e & 15;
            int gk = (k4 << 2);
            const float* src = (gk < K1) ? (A1 + (size_t)r * K1 + gk)
                                         : (A2 + (size_t)r * K2 + (gk - K1));
            pa[q] = *(const float4*)src;
        }
        #pragma unroll
        for (int q = 0; q < 2; ++q) {
            int e = tid + (q << 9);
            int k = e >> 4, c = e & 15;
            pw[q] = W[(size_t)k * SDIM + (c >> 2) * HN + colbase + (c & 3)];
        }
    }

    for (int kb = 0; kb < NKB; ++kb) {
        __syncthreads();                       // prev compute done reading LDS
        // commit prefetched tile to LDS
        #pragma unroll
        for (int q = 0; q < 2; ++q) {
            int e = tid + (q << 9);
            int r = e >> 4, k4 = e & 15;
            As[(k4 << 2) + 0][r] = pa[q].x;
            As[(k4 << 2) + 1][r] = pa[q].y;
            As[(k4 << 2) + 2][r] = pa[q].z;
            As[(k4 << 2) + 3][r] = pa[q].w;
        }
        #pragma unroll
        for (int q = 0; q < 2; ++q) {
            int e = tid + (q << 9);
            int k = e >> 4, c = e & 15;
            Ws[k][c] = pw[q];
        }
        __syncthreads();
        // issue next-tile prefetch BEFORE compute: HBM/L3 latency hides under FMAs
        if (kb + 1 < NKB) {
            const int kk = (kb + 1) << 6;
            #pragma unroll
            for (int q = 0; q < 2; ++q) {
                int e = tid + (q << 9);
                int r = e >> 4, k4 = e & 15;
                int gk = kk + (k4 << 2);
                const float* src = (gk < K1) ? (A1 + (size_t)r * K1 + gk)
                                             : (A2 + (size_t)r * K2 + (gk - K1));
                pa[q] = *(const float4*)src;
            }
            #pragma unroll
            for (int q = 0; q < 2; ++q) {
                int e = tid + (q << 9);
                int k = e >> 4, c = e & 15;
                pw[q] = W[(size_t)(kk + k) * SDIM + (c >> 2) * HN + colbase + (c & 3)];
            }
        }
        // compute: this wave's 8 k's of the staged 64
        #pragma unroll
        for (int k8 = 0; k8 < 8; ++k8) {
            int k = (wv << 3) + k8;
            float2 a01 = *(const float2*)&As[k][r0];
            float2 a23 = *(const float2*)&As[k][r0 + 2];
            float4 w4  = *(const float4*)&Ws[k][c0];
            float a[4]  = {a01.x, a01.y, a23.x, a23.y};
            float wr[4] = {w4.x, w4.y, w4.z, w4.w};
            #pragma unroll
            for (int i = 0; i < 4; ++i)
                #pragma unroll
                for (int j = 0; j < 4; ++j)
                    acc[i][j] = fmaf(a[i], wr[j], acc[i][j]);
        }
    }

    // deterministic cross-wave reduction
    #pragma unroll
    for (int i = 0; i < 4; ++i)
        #pragma unroll
        for (int j = 0; j < 4; ++j)
            Pred[wv][lane][(i << 2) + j] = acc[i][j];
    __syncthreads();

    #pragma unroll
    for (int u = 0; u < 2; ++u) {
        int e = (tid << 1) + u;
        int p = e >> 4, ij = e & 15;
        float v = 0.0f;
        #pragma unroll
        for (int w = 0; w < 8; ++w) v += Pred[w][p][ij];   // fixed order
        int i = ij >> 2, j = ij & 3;
        int r  = ((p & 15) << 2) + i;
        int cl = ((p >> 4) << 2) + j;
        int scol = (cl >> 2) * HN + colbase + (cl & 3);
        Sx[cl][r] = v + bias[scol];
    }
    __syncthreads();

    if (tid < 256) {
        int r = tid & 63, ii = tid >> 6;
        float fg = sigmoidf_(Sx[ii][r]);
        float ig = sigmoidf_(Sx[4 + ii][r]);
        float og = sigmoidf_(Sx[8 + ii][r]);
        float gg = tanhf(Sx[12 + ii][r]);
        int cidx = r * HN + colbase + ii;
        float cn = fg * cst[cidx] + ig * gg;
        float hn = og * tanhf(cn);
        cst[cidx]   = cn;
        h_out[cidx] = hn;
        if (hs_out) hs_out[cidx] = hn;
    }
}

// ---------------------------------------------------------------------------
// Parallel GEMM: C[M,N] = A[M,K] @ B[K,N] (+bias, opt relu).
// 128x64 tile, 256 threads, 8x4 micro. M%128==0, N%64==0, K%16==0.
// ---------------------------------------------------------------------------
__global__ __launch_bounds__(256)
void gemm128(const float* __restrict__ A, const float* __restrict__ B,
             const float* __restrict__ bias, float* __restrict__ C,
             int M, int N, int K, int relu)
{
    __shared__ float As[16][132];   // stride 132 -> 16B-aligned float4 reads
    __shared__ float Bs[16][64];

    const int tid = threadIdx.x;
    const int tx = tid & 15, ty = tid >> 4;
    const int m0 = blockIdx.y << 7, n0 = blockIdx.x << 6;
    float acc[8][4] = {};

    for (int kk = 0; kk < K; kk += 16) {
        #pragma unroll
        for (int i = 0; i < 8; ++i) {
            int e = tid + (i << 8);
            int r = e >> 4, k = e & 15;
            As[k][r] = A[(size_t)(m0 + r) * K + kk + k];
        }
        #pragma unroll
        for (int i = 0; i < 4; ++i) {
            int e = tid + (i << 8);
            int r = e >> 6, c = e & 63;
            Bs[r][c] = B[(size_t)(kk + r) * N + n0 + c];
        }
        __syncthreads();
        #pragma unroll
        for (int k = 0; k < 16; ++k) {
            float4 a0 = *(const float4*)&As[k][(ty << 3)];
            float4 a1 = *(const float4*)&As[k][(ty << 3) + 4];
            float4 b4 = *(const float4*)&Bs[k][(tx << 2)];
            float a[8] = {a0.x, a0.y, a0.z, a0.w, a1.x, a1.y, a1.z, a1.w};
            float b[4] = {b4.x, b4.y, b4.z, b4.w};
            #pragma unroll
            for (int i = 0; i < 8; ++i)
                #pragma unroll
                for (int j = 0; j < 4; ++j)
                    acc[i][j] = fmaf(a[i], b[j], acc[i][j]);
        }
        __syncthreads();
    }

    #pragma unroll
    for (int i = 0; i < 8; ++i) {
        int gm = m0 + (ty << 3) + i;
        float4 o;
        float* op = (float*)&o;
        #pragma unroll
        for (int j = 0; j < 4; ++j) {
            int gn = n0 + (tx << 2) + j;
            float v = acc[i][j] + (bias ? bias[gn] : 0.0f);
            if (relu) v = fmaxf(v, 0.0f);
            op[j] = v;
        }
        *(float4*)&C[(size_t)gm * N + n0 + (tx << 2)] = o;
    }
}

__global__ __launch_bounds__(256)
void init_states(const float* __restrict__ a, const float* __restrict__ b,
                 const float* __restrict__ cc, const float* __restrict__ d,
                 float* __restrict__ oa, float* __restrict__ ob,
                 float* __restrict__ oc, float* __restrict__ od, int n)
{
    int i = blockIdx.x * 256 + threadIdx.x;
    if (i < n) { oa[i] = a[i]; ob[i] = b[i]; oc[i] = cc[i]; od[i] = d[i]; }
}

extern "C" void kernel_launch(void* const* d_in, const int* in_sizes, int n_in,
                              void* d_out, int out_size, void* d_ws, size_t ws_size,
                              hipStream_t stream) {
    const float* inputs     = (const float*)d_in[0];   // (T,B,V)
    const float* h0_in      = (const float*)d_in[1];
    const float* c0_in      = (const float*)d_in[2];
    const float* h1_in      = (const float*)d_in[3];
    const float* c1_in      = (const float*)d_in[4];
    const float* emb_matrix = (const float*)d_in[5];   // (V,E)
    const float* lstm_w0    = (const float*)d_in[6];   // (E+HN, 4HN)
    const float* lstm_b0    = (const float*)d_in[7];
    const float* lstm_w1    = (const float*)d_in[8];   // (2HN, 4HN)
    const float* lstm_b1    = (const float*)d_in[9];
    const float* out_w0     = (const float*)d_in[10];  // (HN, ON)
    const float* out_b0     = (const float*)d_in[11];
    const float* out_w1     = (const float*)d_in[12];  // (ON, V)
    const float* out_b1     = (const float*)d_in[13];
    float* logits = (float*)d_out;                     // (T*B, V)

    const int MB = T_STEPS * BATCH;  // 12800

    // workspace (floats): ~127 MB
    float* ws   = (float*)d_ws;
    float* emb  = ws;                                   // 12800*512
    float* hb0  = emb + (size_t)MB * EMB;               // 2 * B*HN (ping-pong)
    float* hb1  = hb0 + 2 * (size_t)BATCH * HN;         // 2 * B*HN
    float* c0s  = hb1 + 2 * (size_t)BATCH * HN;
    float* c1s  = c0s + (size_t)BATCH * HN;
    float* HS   = c1s + (size_t)BATCH * HN;             // T*B*HN
    float* hid  = HS  + (size_t)MB * HN;                // T*B*ON

    init_states<<<dim3((BATCH * HN + 255) / 256), 256, 0, stream>>>(
        h0_in, c0_in, h1_in, c1_in, hb0, c0s, hb1, c1s, BATCH * HN);

    // emb = inputs @ emb_matrix   (12800 x 256) @ (256 x 512)
    gemm128<<<dim3(EMB / 64, MB / 128), 256, 0, stream>>>(
        inputs, emb_matrix, nullptr, emb, MB, EMB, VOCAB, 0);

    for (int t = 0; t < T_STEPS; ++t) {
        int cur = t & 1;
        float* h0r = hb0 + (size_t)cur * BATCH * HN;
        float* h0w = hb0 + (size_t)(cur ^ 1) * BATCH * HN;
        float* h1r = hb1 + (size_t)cur * BATCH * HN;
        float* h1w = hb1 + (size_t)(cur ^ 1) * BATCH * HN;
        // layer 0: [emb_t, h0] @ W0 + b0 -> gates -> h0,c0
        lstm_cell<<<dim3(HN / 4), 512, 0, stream>>>(
            emb + (size_t)t * BATCH * EMB, EMB, h0r, HN,
            lstm_w0, lstm_b0, c0s, h0w, nullptr);
        // layer 1: [h0_new, h1] @ W1 + b1 -> gates -> h1,c1, store HS[t]
        lstm_cell<<<dim3(HN / 4), 512, 0, stream>>>(
            h0w, HN, h1r, HN,
            lstm_w1, lstm_b1, c1s, h1w, HS + (size_t)t * BATCH * HN);
    }

    // hid = relu(HS @ out_w0 + out_b0)   (12800 x 1024) @ (1024 x 1024)
    gemm128<<<dim3(ON_ / 64, MB / 128), 256, 0, stream>>>(
        HS, out_w0, out_b0, hid, MB, ON_, HN, 1);

    // logits = hid @ out_w1 + out_b1     (12800 x 1024) @ (1024 x 256)
    gemm128<<<dim3(VOCAB / 64, MB / 128), 256, 0, stream>>>(
        hid, out_w1, out_b1, logits, MB, VOCAB, ON_, 0);
}